// Round 1
// baseline (231.766 us; speedup 1.0000x reference)
//
#include <hip/hip_runtime.h>

// EnhancedHamiltonianEvolution: out = Hamilton(ql_n, Hamilton(g*x, conj(qr_n)))
// FFT removed: spectral_gate is constant along the transform (time) axis,
// so ifft(fft(x)*g).real == g*x exactly by DFT linearity.

constexpr int D_MODEL = 2048;
constexpr int QD      = 512;       // QUAT_DIM
constexpr int NF4     = QD / 4;    // 128 float4 groups per component row

__device__ __forceinline__ void quat_one(
    float xw, float xx, float xy, float xz,      // input quaternion (one feature)
    float lw, float lx, float ly, float lz,      // raw q_left
    float rw, float rx, float ry, float rz,      // raw q_right
    float g,
    float& ow, float& ox, float& oy, float& oz)
{
    const float eps = 1e-8f;
    float linv = rsqrtf(lw*lw + lx*lx + ly*ly + lz*lz + eps);
    lw *= linv; lx *= linv; ly *= linv; lz *= linv;
    float rinv = rsqrtf(rw*rw + rx*rx + ry*ry + rz*rz + eps);
    // normalized conjugate of q_right
    float cw =  rw * rinv;
    float cx = -rx * rinv;
    float cy = -ry * rinv;
    float cz = -rz * rinv;
    // gate (exact replacement of fft->gate->ifft since gate is freq-constant)
    float aw = xw * g, ax = xx * g, ay = xy * g, az = xz * g;
    // t = H(a, c)   [x_filt * qr_conj]
    float tw = aw*cw - ax*cx - ay*cy - az*cz;
    float tx = aw*cx + ax*cw + ay*cz - az*cy;
    float ty = aw*cy - ax*cz + ay*cw + az*cx;
    float tz = aw*cz + ax*cy - ay*cx + az*cw;
    // o = H(l, t)   [ql * t]
    ow = lw*tw - lx*tx - ly*ty - lz*tz;
    ox = lw*tx + lx*tw + ly*tz - lz*ty;
    oy = lw*ty - lx*tz + ly*tw + lz*tx;
    oz = lw*tz + lx*ty - ly*tx + lz*tw;
}

__global__ __launch_bounds__(256) void quat_rot_kernel(
    const float* __restrict__ x,
    const float* __restrict__ q_left,
    const float* __restrict__ q_right,
    const float* __restrict__ gate,
    float* __restrict__ out,
    int n_bt)
{
    int idx = blockIdx.x * blockDim.x + threadIdx.x;
    int f4  = idx & (NF4 - 1);
    int bt  = idx >> 7;               // / NF4
    if (bt >= n_bt) return;
    int f = f4 << 2;

    // q params for 4 consecutive features (tiny arrays, L1-resident)
    const float4 lw4 = *(const float4*)(q_left  + 0 * QD + f);
    const float4 lx4 = *(const float4*)(q_left  + 1 * QD + f);
    const float4 ly4 = *(const float4*)(q_left  + 2 * QD + f);
    const float4 lz4 = *(const float4*)(q_left  + 3 * QD + f);
    const float4 rw4 = *(const float4*)(q_right + 0 * QD + f);
    const float4 rx4 = *(const float4*)(q_right + 1 * QD + f);
    const float4 ry4 = *(const float4*)(q_right + 2 * QD + f);
    const float4 rz4 = *(const float4*)(q_right + 3 * QD + f);
    const float4 g4  = *(const float4*)(gate + f);

    size_t base = (size_t)bt * D_MODEL + f;
    const float4 xw4 = *(const float4*)(x + base + 0 * QD);
    const float4 xx4 = *(const float4*)(x + base + 1 * QD);
    const float4 xy4 = *(const float4*)(x + base + 2 * QD);
    const float4 xz4 = *(const float4*)(x + base + 3 * QD);

    float4 ow4, ox4, oy4, oz4;
    quat_one(xw4.x, xx4.x, xy4.x, xz4.x, lw4.x, lx4.x, ly4.x, lz4.x,
             rw4.x, rx4.x, ry4.x, rz4.x, g4.x, ow4.x, ox4.x, oy4.x, oz4.x);
    quat_one(xw4.y, xx4.y, xy4.y, xz4.y, lw4.y, lx4.y, ly4.y, lz4.y,
             rw4.y, rx4.y, ry4.y, rz4.y, g4.y, ow4.y, ox4.y, oy4.y, oz4.y);
    quat_one(xw4.z, xx4.z, xy4.z, xz4.z, lw4.z, lx4.z, ly4.z, lz4.z,
             rw4.z, rx4.z, ry4.z, rz4.z, g4.z, ow4.z, ox4.z, oy4.z, oz4.z);
    quat_one(xw4.w, xx4.w, xy4.w, xz4.w, lw4.w, lx4.w, ly4.w, lz4.w,
             rw4.w, rx4.w, ry4.w, rz4.w, g4.w, ow4.w, ox4.w, oy4.w, oz4.w);

    *(float4*)(out + base + 0 * QD) = ow4;
    *(float4*)(out + base + 1 * QD) = ox4;
    *(float4*)(out + base + 2 * QD) = oy4;
    *(float4*)(out + base + 3 * QD) = oz4;
}

extern "C" void kernel_launch(void* const* d_in, const int* in_sizes, int n_in,
                              void* d_out, int out_size, void* d_ws, size_t ws_size,
                              hipStream_t stream) {
    const float* x      = (const float*)d_in[0];
    const float* q_left = (const float*)d_in[1];
    const float* q_right= (const float*)d_in[2];
    const float* gate   = (const float*)d_in[3];
    float* out          = (float*)d_out;

    int n_bt = in_sizes[0] / D_MODEL;          // B*T = 16384
    long total = (long)n_bt * NF4;             // threads
    int block = 256;
    int grid = (int)((total + block - 1) / block);
    quat_rot_kernel<<<grid, block, 0, stream>>>(x, q_left, q_right, gate, out, n_bt);
}